// Round 1
// baseline (42.534 us; speedup 1.0000x reference)
//
#include <hip/hip_runtime.h>
#include <math.h>
#include <float.h>

// Problem constants (reference: N=8192, IN_DIM=1, UNITS=64)
#define NROWS 8192
#define D     64
#define EPSN  1e-12f

__device__ __forceinline__ float wave_reduce_sum(float v) {
    #pragma unroll
    for (int m = 1; m < 64; m <<= 1) v += __shfl_xor(v, m, 64);
    return v;
}

__device__ __forceinline__ float wave_reduce_min(float v) {
    #pragma unroll
    for (int m = 1; m < 64; m <<= 1) v = fminf(v, __shfl_xor(v, m, 64));
    return v;
}

// K1: emb[i][j] = x[i]*W[j] + b[j]; inv_n[i] = 1/sqrt(max(sum_j emb^2, EPS))
// 256 threads = 4 waves, one row per wave (64 lanes = 64 units).
__global__ void k_emb(const float* __restrict__ x, const float* __restrict__ W,
                      const float* __restrict__ b, float* __restrict__ emb,
                      float* __restrict__ inv_n) {
    const int tid = threadIdx.x;
    const int row = blockIdx.x * 4 + (tid >> 6);
    const int j = tid & 63;
    const float e = fmaf(x[row], W[j], b[j]);
    emb[row * D + j] = e;
    const float s = wave_reduce_sum(e * e);
    if (j == 0) {
        const float norm = sqrtf(fmaxf(s, EPSN));
        inv_n[row] = 1.0f / norm;
    }
}

// K2: loss[i] = 1 - min_j |emb_i . emb_j| / (n_i n_j), using the rank-1 identity
//   emb_i . emb_j = x_i x_j wTw + (x_i + x_j) wTb + bTb  (exact, IN_DIM=1)
// One block (256 threads) per i; j strided across threads.
__global__ void k_loss(const float* __restrict__ x, const float* __restrict__ W,
                       const float* __restrict__ b, const float* __restrict__ inv_n,
                       float* __restrict__ loss) {
    __shared__ float s_dots[3];
    __shared__ float s_min[4];
    const int tid = threadIdx.x;

    // Wave 0 computes wTw, wTb, bTb (D=64, one element per lane).
    if (tid < 64) {
        const float w = W[tid];
        const float bb = b[tid];
        const float ww  = wave_reduce_sum(w * w);
        const float wb  = wave_reduce_sum(w * bb);
        const float bsq = wave_reduce_sum(bb * bb);
        if (tid == 0) { s_dots[0] = ww; s_dots[1] = wb; s_dots[2] = bsq; }
    }
    __syncthreads();

    const int i = blockIdx.x;
    const float xi  = x[i];
    const float wTw = s_dots[0];
    const float wTb = s_dots[1];
    const float bTb = s_dots[2];
    // num(i,j) = A*x_j + C
    const float A = fmaf(xi, wTw, wTb);
    const float C = fmaf(xi, wTb, bTb);

    float m = FLT_MAX;
    for (int j = tid; j < NROWS; j += 256) {
        const float v = fabsf(fmaf(A, x[j], C)) * inv_n[j];
        m = fminf(m, v);
    }
    m = wave_reduce_min(m);
    if ((tid & 63) == 0) s_min[tid >> 6] = m;
    __syncthreads();
    if (tid == 0) {
        m = fminf(fminf(s_min[0], s_min[1]), fminf(s_min[2], s_min[3]));
        loss[i] = 1.0f - m * inv_n[i];
    }
}

// K3: aux = -(mean_i loss[i]); single block, deterministic fixed-order reduce.
__global__ void k_reduce(const float* __restrict__ loss, float* __restrict__ out_aux) {
    __shared__ float s[16];
    const int tid = threadIdx.x;  // 1024 threads = 16 waves
    float sum = 0.0f;
    for (int i = tid; i < NROWS; i += 1024) sum += loss[i];
    sum = wave_reduce_sum(sum);
    if ((tid & 63) == 0) s[tid >> 6] = sum;
    __syncthreads();
    if (tid == 0) {
        float v = 0.0f;
        #pragma unroll
        for (int k = 0; k < 16; ++k) v += s[k];
        out_aux[0] = -(v / (float)NROWS);
    }
}

extern "C" void kernel_launch(void* const* d_in, const int* in_sizes, int n_in,
                              void* d_out, int out_size, void* d_ws, size_t ws_size,
                              hipStream_t stream) {
    const float* x = (const float*)d_in[0];   // [8192, 1]
    const float* W = (const float*)d_in[1];   // [1, 64]
    const float* b = (const float*)d_in[2];   // [64]

    float* emb = (float*)d_out;               // [8192, 64]
    float* aux = (float*)d_out + NROWS * D;   // scalar

    float* inv_n = (float*)d_ws;              // [8192]
    float* loss  = (float*)d_ws + NROWS;      // [8192]

    k_emb<<<NROWS / 4, 256, 0, stream>>>(x, W, b, emb, inv_n);
    k_loss<<<NROWS, 256, 0, stream>>>(x, W, b, inv_n, loss);
    k_reduce<<<1, 1024, 0, stream>>>(loss, aux);
}

// Round 2
// 28.378 us; speedup vs baseline: 1.4989x; 1.4989x over previous
//
#include <hip/hip_runtime.h>
#include <math.h>
#include <float.h>

// Problem constants (reference: N=8192, IN_DIM=1, UNITS=64)
#define NROWS 8192
#define D     64
#define EPSN  1e-12f
#define TI    32   // i-rows per block in k_loss2
#define CH    8    // j's preloaded per chunk per thread
#define NCH   4    // chunks: CH*NCH*256 = 8192 = NROWS

__device__ __forceinline__ float wave_reduce_sum(float v) {
    #pragma unroll
    for (int m = 1; m < 64; m <<= 1) v += __shfl_xor(v, m, 64);
    return v;
}

__device__ __forceinline__ float wave_reduce_min(float v) {
    #pragma unroll
    for (int m = 1; m < 64; m <<= 1) v = fminf(v, __shfl_xor(v, m, 64));
    return v;
}

// K1: emb[i][j] = x[i]*W[j] + b[j]; inv_n[i] = 1/sqrt(max(sum_j emb^2, EPS))
// 256 threads = 4 waves, one row per wave (64 lanes = 64 units).
__global__ void k_emb(const float* __restrict__ x, const float* __restrict__ W,
                      const float* __restrict__ b, float* __restrict__ emb,
                      float* __restrict__ inv_n) {
    const int tid = threadIdx.x;
    const int row = blockIdx.x * 4 + (tid >> 6);
    const int j = tid & 63;
    const float e = fmaf(x[row], W[j], b[j]);
    emb[row * D + j] = e;
    const float s = wave_reduce_sum(e * e);
    if (j == 0) {
        const float norm = sqrtf(fmaxf(s, EPSN));
        inv_n[row] = 1.0f / norm;
    }
}

// K2: loss[i] = 1 - min_j |emb_i . emb_j| * inv_n[i] * inv_n[j], via rank-1 identity
//   emb_i . emb_j = x_i x_j wTw + (x_i + x_j) wTb + bTb   (exact for IN_DIM=1)
// Block handles TI=32 consecutive i's; each thread register-caches its j-slice
// so x/inv_n are read once per block instead of once per i.
__global__ __launch_bounds__(256) void k_loss2(
        const float* __restrict__ x, const float* __restrict__ W,
        const float* __restrict__ b, const float* __restrict__ inv_n,
        float* __restrict__ loss) {
    __shared__ float s_dots[3];
    __shared__ float sAC[TI * 2];     // A,C interleaved per i
    __shared__ float s_part[4][TI];   // per-wave partial mins
    const int tid = threadIdx.x;

    // Wave 0: wTw, wTb, bTb (D=64, one element per lane).
    if (tid < 64) {
        const float w  = W[tid];
        const float bb = b[tid];
        const float ww  = wave_reduce_sum(w * w);
        const float wb  = wave_reduce_sum(w * bb);
        const float bsq = wave_reduce_sum(bb * bb);
        if (tid == 0) { s_dots[0] = ww; s_dots[1] = wb; s_dots[2] = bsq; }
    }
    __syncthreads();

    const int i0 = blockIdx.x * TI;
    if (tid < TI) {
        const float xi = x[i0 + tid];
        sAC[2 * tid]     = fmaf(xi, s_dots[0], s_dots[1]);  // A_i
        sAC[2 * tid + 1] = fmaf(xi, s_dots[1], s_dots[2]);  // C_i
    }
    __syncthreads();

    float m[TI];
    #pragma unroll
    for (int ii = 0; ii < TI; ++ii) m[ii] = FLT_MAX;

    for (int c = 0; c < NCH; ++c) {           // runtime loop: keeps code size sane
        float xj[CH], ivj[CH];
        #pragma unroll
        for (int k = 0; k < CH; ++k) {        // coalesced: lanes read consecutive j
            const int j = tid + (c * CH + k) * 256;
            xj[k]  = x[j];
            ivj[k] = inv_n[j];
        }
        #pragma unroll
        for (int ii = 0; ii < TI; ++ii) {
            const float A = sAC[2 * ii];      // wave-uniform LDS broadcast
            const float C = sAC[2 * ii + 1];
            float mm = m[ii];
            #pragma unroll
            for (int k = 0; k < CH; ++k) {
                mm = fminf(mm, fabsf(fmaf(A, xj[k], C)) * ivj[k]);
            }
            m[ii] = mm;
        }
    }

    // Reduce each i across the block: wave shuffle-min, then 4-wave LDS combine.
    const int wv = tid >> 6, ln = tid & 63;
    #pragma unroll
    for (int ii = 0; ii < TI; ++ii) {
        const float mm = wave_reduce_min(m[ii]);
        if (ln == 0) s_part[wv][ii] = mm;
    }
    __syncthreads();
    if (tid < TI) {
        const float mm = fminf(fminf(s_part[0][tid], s_part[1][tid]),
                               fminf(s_part[2][tid], s_part[3][tid]));
        loss[i0 + tid] = 1.0f - mm * inv_n[i0 + tid];
    }
}

// K3: aux = -(mean_i loss[i]); single block, deterministic fixed-order reduce.
__global__ void k_reduce(const float* __restrict__ loss, float* __restrict__ out_aux) {
    __shared__ float s[16];
    const int tid = threadIdx.x;  // 1024 threads = 16 waves
    float sum = 0.0f;
    for (int i = tid; i < NROWS; i += 1024) sum += loss[i];
    sum = wave_reduce_sum(sum);
    if ((tid & 63) == 0) s[tid >> 6] = sum;
    __syncthreads();
    if (tid == 0) {
        float v = 0.0f;
        #pragma unroll
        for (int k = 0; k < 16; ++k) v += s[k];
        out_aux[0] = -(v / (float)NROWS);
    }
}

extern "C" void kernel_launch(void* const* d_in, const int* in_sizes, int n_in,
                              void* d_out, int out_size, void* d_ws, size_t ws_size,
                              hipStream_t stream) {
    const float* x = (const float*)d_in[0];   // [8192, 1]
    const float* W = (const float*)d_in[1];   // [1, 64]
    const float* b = (const float*)d_in[2];   // [64]

    float* emb = (float*)d_out;               // [8192, 64]
    float* aux = (float*)d_out + NROWS * D;   // scalar

    float* inv_n = (float*)d_ws;              // [8192]
    float* loss  = (float*)d_ws + NROWS;      // [8192]

    k_emb<<<NROWS / 4, 256, 0, stream>>>(x, W, b, emb, inv_n);
    k_loss2<<<NROWS / TI, 256, 0, stream>>>(x, W, b, inv_n, loss);
    k_reduce<<<1, 1024, 0, stream>>>(loss, aux);
}

// Round 3
// 13.138 us; speedup vs baseline: 3.2376x; 2.1601x over previous
//
#include <hip/hip_runtime.h>
#include <math.h>
#include <float.h>

// Problem constants (reference: N=8192, IN_DIM=1, UNITS=64)
#define NROWS 8192
#define D     64
#define EPSN  1e-12f
#define TI    16                 // i-rows per block in k_main
#define NBLK  (NROWS / TI)       // 512 blocks
#define JPT   (NROWS / 256)      // 32 j's register-cached per thread

__device__ __forceinline__ float wave_reduce_sum(float v) {
    #pragma unroll
    for (int m = 1; m < 64; m <<= 1) v += __shfl_xor(v, m, 64);
    return v;
}

// Fused kernel: per block b
//   - writes emb rows [16b, 16b+16)  (emb = x*W + b, float4-coalesced)
//   - computes loss_i = 1 - min_j |cos(i,j)| for its 16 i's via the rank-1
//     identities (exact for IN_DIM=1):
//       emb_i.emb_j = x_i x_j wTw + (x_i+x_j) wTb + bTb = A_i x_j + C_i
//       ||emb_j||^2 = x_j^2 wTw + 2 x_j wTb + bTb
//   - writes partial[b] = sum of its 16 loss values (all fixed-order -> deterministic)
__global__ __launch_bounds__(256) void k_main(
        const float* __restrict__ x, const float* __restrict__ W,
        const float* __restrict__ b, float* __restrict__ emb,
        float* __restrict__ partial) {
    __shared__ float s_dots[3];
    __shared__ float sAC[TI * 2];
    __shared__ float red[TI][257];    // +1 pad: break stride-16 bank aliasing
    __shared__ float red2[TI][17];
    __shared__ float l16[TI];
    const int tid = threadIdx.x;
    const int blk = blockIdx.x;
    const int i0  = blk * TI;

    // ---- emb write: 16 rows, one float4 per thread, fully coalesced ----
    {
        const int r  = tid >> 4;          // row within tile, 0..15
        const int c4 = tid & 15;          // float4 column index, 0..15
        const float xr = x[i0 + r];
        const float4 w4 = ((const float4*)W)[c4];
        const float4 b4 = ((const float4*)b)[c4];
        float4 e;
        e.x = fmaf(xr, w4.x, b4.x);
        e.y = fmaf(xr, w4.y, b4.y);
        e.z = fmaf(xr, w4.z, b4.z);
        e.w = fmaf(xr, w4.w, b4.w);
        ((float4*)emb)[blk * 256 + tid] = e;
    }

    // ---- wave 0: wTw, wTb, bTb ----
    if (tid < 64) {
        const float w  = W[tid];
        const float bb = b[tid];
        const float ww = wave_reduce_sum(w * w);
        const float wb = wave_reduce_sum(w * bb);
        const float bq = wave_reduce_sum(bb * bb);
        if (tid == 0) { s_dots[0] = ww; s_dots[1] = wb; s_dots[2] = bq; }
    }
    __syncthreads();
    const float wTw = s_dots[0], wTb = s_dots[1], bTb = s_dots[2];

    if (tid < TI) {
        const float xi = x[i0 + tid];
        sAC[2 * tid]     = fmaf(xi, wTw, wTb);   // A_i
        sAC[2 * tid + 1] = fmaf(xi, wTb, bTb);   // C_i
    }

    // ---- preload per-thread j-slice, norms computed on the fly ----
    float xj[JPT], ivj[JPT];
    #pragma unroll
    for (int k = 0; k < JPT; ++k) {
        const float v = x[tid + k * 256];        // coalesced
        xj[k] = v;
        const float nsq = fmaf(v, fmaf(v, wTw, 2.0f * wTb), bTb);
        ivj[k] = rsqrtf(fmaxf(nsq, EPSN));
    }
    __syncthreads();  // sAC ready

    // ---- pairwise min: ii outer (scalar accumulator, 4-way min tree) ----
    #pragma unroll
    for (int ii = 0; ii < TI; ++ii) {
        const float A = sAC[2 * ii];
        const float C = sAC[2 * ii + 1];
        float m0 = FLT_MAX, m1 = FLT_MAX, m2 = FLT_MAX, m3 = FLT_MAX;
        #pragma unroll
        for (int k = 0; k < JPT; k += 4) {
            m0 = fminf(m0, fabsf(fmaf(A, xj[k    ], C)) * ivj[k    ]);
            m1 = fminf(m1, fabsf(fmaf(A, xj[k + 1], C)) * ivj[k + 1]);
            m2 = fminf(m2, fabsf(fmaf(A, xj[k + 2], C)) * ivj[k + 2]);
            m3 = fminf(m3, fabsf(fmaf(A, xj[k + 3], C)) * ivj[k + 3]);
        }
        red[ii][tid] = fminf(fminf(m0, m1), fminf(m2, m3));
    }
    __syncthreads();

    // ---- 256 -> 16 per i (strided reads; pad keeps banks spread) ----
    {
        const int ii = tid >> 4, s = tid & 15;
        float mn = red[ii][s];
        #pragma unroll
        for (int q = 1; q < 16; ++q) mn = fminf(mn, red[ii][q * 16 + s]);
        red2[ii][s] = mn;
    }
    __syncthreads();

    // ---- 16 -> 1 per i, then block partial sum ----
    if (tid < TI) {
        float mn = red2[tid][0];
        #pragma unroll
        for (int q = 1; q < 16; ++q) mn = fminf(mn, red2[tid][q]);
        const float xi  = x[i0 + tid];
        const float nsq = fmaf(xi, fmaf(xi, wTw, 2.0f * wTb), bTb);
        const float ivi = rsqrtf(fmaxf(nsq, EPSN));
        l16[tid] = 1.0f - mn * ivi;
    }
    __syncthreads();
    if (tid == 0) {
        float s = 0.0f;
        #pragma unroll
        for (int q = 0; q < TI; ++q) s += l16[q];
        partial[blk] = s;
    }
}

// Final: aux = -(sum partials / N); single block, fixed-order -> deterministic.
__global__ void k_fin(const float* __restrict__ partial, float* __restrict__ aux) {
    __shared__ float s4[4];
    const int tid = threadIdx.x;  // 256 threads
    float v = partial[tid] + partial[tid + 256];
    v = wave_reduce_sum(v);
    if ((tid & 63) == 0) s4[tid >> 6] = v;
    __syncthreads();
    if (tid == 0) aux[0] = -((s4[0] + s4[1] + s4[2] + s4[3]) / (float)NROWS);
}

extern "C" void kernel_launch(void* const* d_in, const int* in_sizes, int n_in,
                              void* d_out, int out_size, void* d_ws, size_t ws_size,
                              hipStream_t stream) {
    const float* x = (const float*)d_in[0];   // [8192, 1]
    const float* W = (const float*)d_in[1];   // [1, 64]
    const float* b = (const float*)d_in[2];   // [64]

    float* emb = (float*)d_out;               // [8192, 64]
    float* aux = (float*)d_out + NROWS * D;   // scalar

    float* partial = (float*)d_ws;            // [512]

    k_main<<<NBLK, 256, 0, stream>>>(x, W, b, emb, partial);
    k_fin<<<1, 256, 0, stream>>>(partial, aux);
}